// Round 2
// baseline (218.199 us; speedup 1.0000x reference)
//
#include <hip/hip_runtime.h>

// Problem constants (fixed by reference: XSIZE=128, B=8, N=262144)
constexpr unsigned XS        = 128;
constexpr unsigned NB        = 8;
constexpr unsigned NPTS      = 262144;            // 2^18 per batch
constexpr unsigned TOTAL_PTS = NB * NPTS;         // 2^21
constexpr unsigned NBUCKET   = NB * XS;           // 1024 buckets = (b, i-plane)
constexpr unsigned SHARDS    = 8;                 // cursor sharding to cut atomic contention
constexpr unsigned CAP       = 448;               // per (bucket,shard); mean 256, +12 sigma
constexpr unsigned CNT_STRIDE = 16;               // u32 stride -> one 64B line per counter

// d_ws layout:
//   rec  : u64 [NBUCKET*SHARDS*CAP]              = 29,360,128 B
//   cnt  : u32 [NBUCKET*SHARDS*CNT_STRIDE]       =    524,288 B  (zeroed each call)
//   stage: f32 [16*16]                            =      1,024 B  (zeroed each call)
constexpr size_t REC_U64   = (size_t)NBUCKET * SHARDS * CAP;
constexpr size_t CNT_U32   = (size_t)NBUCKET * SHARDS * CNT_STRIDE;
constexpr size_t CNT_BYTES = CNT_U32 * 4;
constexpr size_t STAGE_BYTES = 16 * 16 * 4;

// ---------------------------------------------------------------------------
// Kernel 1: bucket points by (b, i) into the sharded record buffer.
// Record = [ value_bits : 32 | jk : 32 ].
__global__ __launch_bounds__(256) void reorder_kernel(
        const int* __restrict__ idx, const float* __restrict__ vals,
        unsigned long long* __restrict__ rec, unsigned* __restrict__ cnt) {
    unsigned t = blockIdx.x * 256u + threadIdx.x;         // < 2^21
    unsigned b = t >> 18;
    const int* p = idx + 3ull * t;
    unsigned i = (unsigned)p[0], j = (unsigned)p[1], k = (unsigned)p[2];
    float v = vals[t];
    unsigned bkt   = (b << 7) | i;                        // 0..1023
    unsigned shard = blockIdx.x & (SHARDS - 1u);
    unsigned slot  = bkt * SHARDS + shard;
    unsigned pos   = atomicAdd(cnt + slot * CNT_STRIDE, 1u);
    if (pos < CAP) {
        unsigned jk = (j << 7) | k;
        unsigned long long r =
            ((unsigned long long)__float_as_uint(v) << 32) | jk;
        rec[(size_t)slot * CAP + pos] = r;
    }
}

// ---------------------------------------------------------------------------
// Kernel 2: one block per plane-task. 64KB LDS plane.
//   blocks [0,1024):     d23 task (b,i)  — accumulate P_i, sum j-diffs + k-diffs
//   blocks [1024,2048):  d1  task (b,i)  — accumulate (P_{i+1} - P_i) via signed
//                        adds, sum |D| and D^2.  (i==127 tasks no-op.)
__global__ __launch_bounds__(256) void accum_kernel(
        const unsigned long long* __restrict__ rec,
        const unsigned* __restrict__ cnt, float* __restrict__ stage) {
    __shared__ float plane[XS * XS];                      // 64 KB exactly
    unsigned z = blockIdx.x;
    bool d1mode = z >= NBUCKET;
    unsigned z0 = d1mode ? z - NBUCKET : z;
    unsigned b = z0 >> 7, i = z0 & 127u;
    if (d1mode && i == 127u) return;                      // uniform early exit

    // Zero the LDS plane.
    float4* p4 = (float4*)plane;
    for (unsigned r = threadIdx.x; r < XS * XS / 4; r += 256u)
        p4[r] = float4{0.f, 0.f, 0.f, 0.f};
    __syncthreads();

    // Accumulate records.
    unsigned nbk = d1mode ? 2u : 1u;
    for (unsigned e = 0; e < nbk; ++e) {
        unsigned bkt = (b << 7) | (i + e);
        float sgn = (d1mode && e == 0u) ? -1.f : 1.f;
        for (unsigned s = 0; s < SHARDS; ++s) {
            unsigned slot = bkt * SHARDS + s;
            unsigned c = cnt[slot * CNT_STRIDE];
            if (c > CAP) c = CAP;
            const unsigned long long* base = rec + (size_t)slot * CAP;
            for (unsigned r = threadIdx.x; r < c; r += 256u) {
                unsigned long long rr = base[r];
                unsigned jk = (unsigned)rr & 0x3FFFu;
                float v = __uint_as_float((unsigned)(rr >> 32));
                atomicAdd(plane + jk, sgn * v);
            }
        }
    }
    __syncthreads();

    // Reduce diffs out of LDS.
    float tv = 0.f, mse = 0.f;
    if (d1mode) {
#pragma unroll 4
        for (unsigned r = 0; r < 64u; ++r) {
            float d = plane[r * 256u + threadIdx.x];
            tv += fabsf(d); mse += d * d;
        }
    } else {
#pragma unroll 4
        for (unsigned r = 0; r < 64u; ++r) {
            unsigned v = r * 256u + threadIdx.x;
            unsigned j = v >> 7, k = v & 127u;
            float c = plane[v];
            if (j < 127u) { float d = plane[v + 128u] - c; tv += fabsf(d); mse += d * d; }
            if (k < 127u) { float d = plane[v + 1u]   - c; tv += fabsf(d); mse += d * d; }
        }
    }

    // Wave shuffle reduce, then cross-wave via (now-reusable) plane[0..12).
#pragma unroll
    for (int o = 32; o > 0; o >>= 1) {
        tv  += __shfl_down(tv, o, 64);
        mse += __shfl_down(mse, o, 64);
    }
    __syncthreads();                                      // all plane reads done
    unsigned lane = threadIdx.x & 63u, w = threadIdx.x >> 6;
    if (lane == 0u) { plane[w] = tv; plane[8u + w] = mse; }
    __syncthreads();
    if (threadIdx.x == 0u) {
        float tt = plane[0] + plane[1] + plane[2] + plane[3];
        float mm = plane[8] + plane[9] + plane[10] + plane[11];
        atomicAdd(stage + (size_t)b * 16u,        tt);    // tv slot
        atomicAdd(stage + (size_t)(8u + b) * 16u, mm);    // mse slot
    }
}

// ---------------------------------------------------------------------------
// Kernel 3: scale staged sums into d_out (overwrites poison).
__global__ void finalize_kernel(const float* __restrict__ stage,
                                float* __restrict__ out) {
    unsigned i = threadIdx.x;
    if (i < 16u) {
        float s = stage[i * 16u];
        float scale = (i < 8u) ? (1.0f / 2097152.0f)      // / 128^3
                               : (1.0f / 32512.0f);       // / (2*128^2 - 2*128)
        out[i] = s * scale;
    }
}

// ---------------------------------------------------------------------------
extern "C" void kernel_launch(void* const* d_in, const int* in_sizes, int n_in,
                              void* d_out, int out_size, void* d_ws, size_t ws_size,
                              hipStream_t stream) {
    const int*   idx  = (const int*)d_in[0];    // [8, 262144, 3] int32
    const float* vals = (const float*)d_in[1];  // [8, 262144] float32

    unsigned long long* rec = (unsigned long long*)d_ws;
    unsigned* cnt   = (unsigned*)(rec + REC_U64);
    float*    stage = (float*)((char*)cnt + CNT_BYTES);
    float*    out   = (float*)d_out;

    // Zero counters + staging only (d_ws is re-poisoned to 0xAA each call).
    hipMemsetAsync(cnt, 0, CNT_BYTES + STAGE_BYTES, stream);

    reorder_kernel<<<TOTAL_PTS / 256, 256, 0, stream>>>(idx, vals, rec, cnt);
    accum_kernel<<<2 * NBUCKET, 256, 0, stream>>>(rec, cnt, stage);
    finalize_kernel<<<1, 64, 0, stream>>>(stage, out);
}

// Round 3
// 158.488 us; speedup vs baseline: 1.3768x; 1.3768x over previous
//
#include <hip/hip_runtime.h>

// Problem constants (fixed by reference: XSIZE=128, B=8, N=262144)
constexpr unsigned XS        = 128;
constexpr unsigned NB        = 8;
constexpr unsigned NPTS      = 262144;           // 2^18 per batch
constexpr unsigned TOTAL_PTS = NB * NPTS;        // 2^21
constexpr unsigned PPB       = 4096;             // points per sort block
constexpr unsigned NSEG      = TOTAL_PTS / PPB;  // 512 segments
constexpr unsigned SPB       = NPTS / PPB;       // 64 segments per batch

// d_ws layout:
//   rec  : u64 [TOTAL_PTS]        = 16 MiB   (counting-sorted records, fully written)
//   tab  : u32 [NSEG*128]         = 256 KiB  (per-(seg,i): off | cnt<<16, fully written)
//   stage: f32 [16*16]            = 1 KiB    (zeroed each call)
constexpr size_t REC_U64     = (size_t)TOTAL_PTS;
constexpr size_t TAB_U32     = (size_t)NSEG * XS;
constexpr size_t STAGE_BYTES = 16 * 16 * 4;

// ---------------------------------------------------------------------------
// Kernel 1: block-local counting sort by i-plane.
// Block g sorts points [g*4096, (g+1)*4096) (all one batch: 64 blocks/batch)
// into global segment g, grouped by i, and writes the off/cnt table.
__global__ __launch_bounds__(256) void sort_kernel(
        const int* __restrict__ idx, const float* __restrict__ vals,
        unsigned long long* __restrict__ rec, unsigned* __restrict__ tab) {
    __shared__ unsigned long long stg[PPB];      // 32 KiB staging
    __shared__ unsigned hist[XS];
    __shared__ unsigned cur[XS];
    unsigned tid  = threadIdx.x;
    unsigned g    = blockIdx.x;
    unsigned base = g * PPB;

    if (tid < XS) hist[tid] = 0u;
    __syncthreads();

    // Pass 1: read 16 points/thread (coalesced), cache key+value, histogram i.
    unsigned key[16]; float val[16];
#pragma unroll
    for (unsigned n = 0; n < 16; ++n) {
        unsigned pt = base + n * 256u + tid;
        const int* p = idx + 3ull * pt;
        unsigned i = (unsigned)p[0], j = (unsigned)p[1], k = (unsigned)p[2];
        key[n] = (i << 14) | (j << 7) | k;
        val[n] = vals[pt];
        atomicAdd(&hist[i], 1u);
    }
    __syncthreads();

    // Exclusive scan of hist[128] by wave 0 (two 64-wide shuffle scans).
    if (tid < 64u) {
        unsigned h0 = hist[tid], h1 = hist[64u + tid];
        unsigned a0 = h0, a1 = h1;
#pragma unroll
        for (unsigned o = 1; o <= 32; o <<= 1) {
            unsigned t0 = __shfl_up(a0, o, 64);
            unsigned t1 = __shfl_up(a1, o, 64);
            if (tid >= o) { a0 += t0; a1 += t1; }
        }
        a1 += __shfl(a0, 63, 64);                // add total of first half
        unsigned e0 = a0 - h0, e1 = a1 - h1;     // exclusive offsets
        cur[tid] = e0; cur[64u + tid] = e1;
        tab[(size_t)g * XS + tid]       = e0 | (h0 << 16);
        tab[(size_t)g * XS + 64u + tid] = e1 | (h1 << 16);
    }
    __syncthreads();

    // Pass 2: scatter records into LDS staging at sorted positions.
#pragma unroll
    for (unsigned n = 0; n < 16; ++n) {
        unsigned i = key[n] >> 14;
        unsigned pos = atomicAdd(&cur[i], 1u);
        stg[pos] = ((unsigned long long)__float_as_uint(val[n]) << 32)
                 | (unsigned long long)(key[n] & 0x3FFFu);
    }
    __syncthreads();

    // Flush: fully coalesced float4 stores (dense, full lines).
    const float4* s4 = (const float4*)stg;
    float4* d4 = (float4*)(rec + (size_t)base);
    for (unsigned n = tid; n < PPB / 2u; n += 256u) d4[n] = s4[n];
}

// ---------------------------------------------------------------------------
// Kernel 2: one block per plane-task, 64KB LDS plane.
//   blocks [0,1024):    d23 (b,i) — accumulate P_i, sum j-diffs + k-diffs
//   blocks [1024,2048): d1  (b,i) — accumulate P_{i+1}-P_i (signed adds)
// Per-wave: 16 segments; off/cnt held in lane registers, __shfl-broadcast.
__global__ __launch_bounds__(256) void accum_kernel(
        const unsigned long long* __restrict__ rec,
        const unsigned* __restrict__ tab, float* __restrict__ stage) {
    __shared__ float plane[XS * XS];             // 64 KB
    unsigned z = blockIdx.x;
    bool d1mode = z >= 1024u;
    unsigned z0 = d1mode ? z - 1024u : z;
    unsigned b = z0 >> 7, i = z0 & 127u;
    if (d1mode && i == 127u) return;             // uniform early exit

    unsigned tid = threadIdx.x, lane = tid & 63u, w = tid >> 6;

    // Gather this wave's 16 segment descriptors (and bucket i+1 for d1).
    unsigned myoff = 0u, mycnt = 0u;
    if (lane < 16u) {
        unsigned s = w * 16u + lane;
        unsigned t = tab[(size_t)(b * SPB + s) * XS + i];
        myoff = t & 0xFFFFu; mycnt = t >> 16;
    } else if (d1mode && lane < 32u) {
        unsigned s = w * 16u + (lane - 16u);
        unsigned t = tab[(size_t)(b * SPB + s) * XS + (i + 1u)];
        myoff = t & 0xFFFFu; mycnt = t >> 16;
    }

    // Zero the plane.
    float4* p4 = (float4*)plane;
    for (unsigned r = tid; r < XS * XS / 4u; r += 256u)
        p4[r] = float4{0.f, 0.f, 0.f, 0.f};
    __syncthreads();

    // Accumulate records from 16 segments per wave.
    for (unsigned t = 0; t < 16u; ++t) {
        unsigned seg = b * SPB + w * 16u + t;
        const unsigned long long* sb = rec + (size_t)seg * PPB;
        unsigned o0 = __shfl(myoff, (int)t, 64), c0 = __shfl(mycnt, (int)t, 64);
        if (!d1mode) {
            for (unsigned r = lane; r < c0; r += 64u) {
                unsigned long long rr = sb[o0 + r];
                atomicAdd(&plane[(unsigned)rr & 0x3FFFu],
                          __uint_as_float((unsigned)(rr >> 32)));
            }
        } else {
            unsigned o1 = __shfl(myoff, (int)(16u + t), 64);
            unsigned c1 = __shfl(mycnt, (int)(16u + t), 64);
            for (unsigned r = lane; r < c0; r += 64u) {   // bucket i: -v
                unsigned long long rr = sb[o0 + r];
                atomicAdd(&plane[(unsigned)rr & 0x3FFFu],
                          -__uint_as_float((unsigned)(rr >> 32)));
            }
            for (unsigned r = lane; r < c1; r += 64u) {   // bucket i+1: +v
                unsigned long long rr = sb[o1 + r];
                atomicAdd(&plane[(unsigned)rr & 0x3FFFu],
                          __uint_as_float((unsigned)(rr >> 32)));
            }
        }
    }
    __syncthreads();

    // Reduce diffs out of LDS.
    float tv = 0.f, mse = 0.f;
    if (d1mode) {
#pragma unroll 4
        for (unsigned r = 0; r < 64u; ++r) {
            float d = plane[r * 256u + tid];
            tv += fabsf(d); mse += d * d;
        }
    } else {
#pragma unroll 4
        for (unsigned r = 0; r < 64u; ++r) {
            unsigned v = r * 256u + tid;
            unsigned j = v >> 7, k = v & 127u;
            float c = plane[v];
            if (j < 127u) { float d = plane[v + 128u] - c; tv += fabsf(d); mse += d * d; }
            if (k < 127u) { float d = plane[v + 1u]   - c; tv += fabsf(d); mse += d * d; }
        }
    }

    // Wave shuffle reduce, then cross-wave via plane[0..12) (reads done above).
#pragma unroll
    for (int o = 32; o > 0; o >>= 1) {
        tv  += __shfl_down(tv, o, 64);
        mse += __shfl_down(mse, o, 64);
    }
    __syncthreads();
    if (lane == 0u) { plane[w] = tv; plane[8u + w] = mse; }
    __syncthreads();
    if (tid == 0u) {
        float tt = plane[0] + plane[1] + plane[2] + plane[3];
        float mm = plane[8] + plane[9] + plane[10] + plane[11];
        atomicAdd(stage + (size_t)b * 16u,        tt);
        atomicAdd(stage + (size_t)(8u + b) * 16u, mm);
    }
}

// ---------------------------------------------------------------------------
// Kernel 3: scale staged sums into d_out (overwrites poison).
__global__ void finalize_kernel(const float* __restrict__ stage,
                                float* __restrict__ out) {
    unsigned i = threadIdx.x;
    if (i < 16u) {
        float s = stage[i * 16u];
        float scale = (i < 8u) ? (1.0f / 2097152.0f)     // / 128^3
                               : (1.0f / 32512.0f);      // / (2*128^2 - 2*128)
        out[i] = s * scale;
    }
}

// ---------------------------------------------------------------------------
extern "C" void kernel_launch(void* const* d_in, const int* in_sizes, int n_in,
                              void* d_out, int out_size, void* d_ws, size_t ws_size,
                              hipStream_t stream) {
    const int*   idx  = (const int*)d_in[0];    // [8, 262144, 3] int32
    const float* vals = (const float*)d_in[1];  // [8, 262144] float32

    unsigned long long* rec = (unsigned long long*)d_ws;
    unsigned* tab   = (unsigned*)(rec + REC_U64);
    float*    stage = (float*)(tab + TAB_U32);
    float*    out   = (float*)d_out;

    // Zero only the 1 KiB staging slots.
    hipMemsetAsync(stage, 0, STAGE_BYTES, stream);

    sort_kernel<<<NSEG, 256, 0, stream>>>(idx, vals, rec, tab);
    accum_kernel<<<2048, 256, 0, stream>>>(rec, tab, stage);
    finalize_kernel<<<1, 64, 0, stream>>>(stage, out);
}

// Round 4
// 154.993 us; speedup vs baseline: 1.4078x; 1.0225x over previous
//
#include <hip/hip_runtime.h>

// Problem constants (fixed by reference: XSIZE=128, B=8, N=262144)
constexpr unsigned XS        = 128;
constexpr unsigned NB        = 8;
constexpr unsigned NPTS      = 262144;           // 2^18 per batch
constexpr unsigned TOTAL_PTS = NB * NPTS;        // 2^21
constexpr unsigned PPB       = 4096;             // points per sort block
constexpr unsigned NSEG      = TOTAL_PTS / PPB;  // 512 segments
constexpr unsigned SPB       = NPTS / PPB;       // 64 segments per batch

// d_ws layout:
//   rec  : u64 [TOTAL_PTS]        = 16 MiB   (counting-sorted records)
//   tab  : u32 [NSEG*128]         = 256 KiB  (per-(seg,i): off | cnt<<16)
//   stage: f32 [16*16]            = 1 KiB    (zeroed by sort_kernel block 0)
constexpr size_t REC_U64 = (size_t)TOTAL_PTS;
constexpr size_t TAB_U32 = (size_t)NSEG * XS;

// ---------------------------------------------------------------------------
// Kernel 1: block-local counting sort by i-plane. Block g sorts points
// [g*4096,(g+1)*4096) into segment g grouped by i; writes off/cnt table.
// Block 0 additionally zeroes the 256-float stage region (replaces memset).
__global__ __launch_bounds__(256) void sort_kernel(
        const int* __restrict__ idx, const float* __restrict__ vals,
        unsigned long long* __restrict__ rec, unsigned* __restrict__ tab,
        float* __restrict__ stage) {
    __shared__ unsigned long long stg[PPB];      // 32 KiB staging
    __shared__ unsigned hist[XS];
    __shared__ unsigned cur[XS];
    unsigned tid  = threadIdx.x;
    unsigned g    = blockIdx.x;
    unsigned base = g * PPB;

    if (g == 0u) stage[tid] = 0.f;               // 256 floats
    if (tid < XS) hist[tid] = 0u;
    __syncthreads();

    // Pass 1: 16 points/thread (unrolled -> loads pipeline), histogram i.
    unsigned key[16]; float val[16];
#pragma unroll
    for (unsigned n = 0; n < 16; ++n) {
        unsigned pt = base + n * 256u + tid;
        const int* p = idx + 3ull * pt;
        unsigned i = (unsigned)p[0], j = (unsigned)p[1], k = (unsigned)p[2];
        key[n] = (i << 14) | (j << 7) | k;
        val[n] = vals[pt];
        atomicAdd(&hist[i], 1u);
    }
    __syncthreads();

    // Exclusive scan of hist[128] by wave 0.
    if (tid < 64u) {
        unsigned h0 = hist[tid], h1 = hist[64u + tid];
        unsigned a0 = h0, a1 = h1;
#pragma unroll
        for (unsigned o = 1; o <= 32; o <<= 1) {
            unsigned t0 = __shfl_up(a0, o, 64);
            unsigned t1 = __shfl_up(a1, o, 64);
            if (tid >= o) { a0 += t0; a1 += t1; }
        }
        a1 += __shfl(a0, 63, 64);
        unsigned e0 = a0 - h0, e1 = a1 - h1;
        cur[tid] = e0; cur[64u + tid] = e1;
        tab[(size_t)g * XS + tid]       = e0 | (h0 << 16);
        tab[(size_t)g * XS + 64u + tid] = e1 | (h1 << 16);
    }
    __syncthreads();

    // Pass 2: scatter records into LDS staging at sorted positions.
#pragma unroll
    for (unsigned n = 0; n < 16; ++n) {
        unsigned i = key[n] >> 14;
        unsigned pos = atomicAdd(&cur[i], 1u);
        stg[pos] = ((unsigned long long)__float_as_uint(val[n]) << 32)
                 | (unsigned long long)(key[n] & 0x3FFFu);
    }
    __syncthreads();

    // Flush: fully coalesced float4 stores.
    const float4* s4 = (const float4*)stg;
    float4* d4 = (float4*)(rec + (size_t)base);
    for (unsigned n = tid; n < PPB / 2u; n += 256u) d4[n] = s4[n];
}

// ---------------------------------------------------------------------------
// Kernel 2: one block per plane-task, 64 KB LDS plane.
//   blocks [0,1024):    d23 (b,i) — accumulate P_i, sum j-diffs + k-diffs
//   blocks [1024,2048): d1  (b,i) — accumulate P_{i+1}-P_i (signed adds)
// Latency fix: per wave, all 16 segments' records loaded in ONE predicated
// burst (independent dwordx2 loads, single vmcnt drain), then LDS atomics.
__global__ __launch_bounds__(256) void accum_kernel(
        const unsigned long long* __restrict__ rec,
        const unsigned* __restrict__ tab, float* __restrict__ stage) {
    __shared__ float plane[XS * XS];             // 64 KB
    unsigned z = blockIdx.x;
    bool d1mode = z >= 1024u;
    unsigned z0 = d1mode ? z - 1024u : z;
    unsigned b = z0 >> 7, i = z0 & 127u;
    if (d1mode && i == 127u) return;             // uniform early exit

    unsigned tid = threadIdx.x, lane = tid & 63u, w = tid >> 6;

    // Descriptor gather: lanes 0..15 hold bucket-i off/cnt for the wave's 16
    // segments; lanes 16..31 hold bucket-(i+1) (d1 only).
    unsigned myoff = 0u, mycnt = 0u;
    if (lane < 16u) {
        unsigned s = w * 16u + lane;
        unsigned t = tab[(size_t)(b * SPB + s) * XS + i];
        myoff = t & 0xFFFFu; mycnt = t >> 16;
    } else if (d1mode && lane < 32u) {
        unsigned s = w * 16u + (lane - 16u);
        unsigned t = tab[(size_t)(b * SPB + s) * XS + (i + 1u)];
        myoff = t & 0xFFFFu; mycnt = t >> 16;
    }
    // Wave-uniform overflow check (counts > 64 are ~1e-8 rare; mean 32).
    unsigned mx = mycnt;
#pragma unroll
    for (int o = 32; o > 0; o >>= 1) mx = max(mx, __shfl_down(mx, o, 64));
    mx = __shfl(mx, 0, 64);

    // Zero the plane.
    float4* p4 = (float4*)plane;
    for (unsigned r = tid; r < XS * XS / 4u; r += 256u)
        p4[r] = float4{0.f, 0.f, 0.f, 0.f};
    __syncthreads();

    const size_t segbase = (size_t)(b * SPB + w * 16u) * PPB;
    unsigned long long rv[16];
    bool av[16];

    // Phase A: bucket i (negative sign in d1 mode).
    float sgn0 = d1mode ? -1.f : 1.f;
#pragma unroll
    for (unsigned t = 0; t < 16u; ++t) {
        unsigned o = __shfl(myoff, (int)t, 64);
        unsigned c = __shfl(mycnt, (int)t, 64);
        av[t] = lane < c;
        if (av[t]) rv[t] = rec[segbase + (size_t)t * PPB + o + lane];
    }
#pragma unroll
    for (unsigned t = 0; t < 16u; ++t)
        if (av[t])
            atomicAdd(&plane[(unsigned)rv[t] & 0x3FFFu],
                      sgn0 * __uint_as_float((unsigned)(rv[t] >> 32)));

    // Phase B: bucket i+1 (d1 only, positive sign).
    if (d1mode) {
#pragma unroll
        for (unsigned t = 0; t < 16u; ++t) {
            unsigned o = __shfl(myoff, (int)(16u + t), 64);
            unsigned c = __shfl(mycnt, (int)(16u + t), 64);
            av[t] = lane < c;
            if (av[t]) rv[t] = rec[segbase + (size_t)t * PPB + o + lane];
        }
#pragma unroll
        for (unsigned t = 0; t < 16u; ++t)
            if (av[t])
                atomicAdd(&plane[(unsigned)rv[t] & 0x3FFFu],
                          __uint_as_float((unsigned)(rv[t] >> 32)));
    }

    // Rare overflow fallback (any count > 64).
    if (mx > 64u) {
        unsigned npass = d1mode ? 2u : 1u;
        for (unsigned e = 0; e < npass; ++e) {
            float sg = (d1mode && e == 0u) ? -1.f : 1.f;
            for (unsigned t = 0; t < 16u; ++t) {
                unsigned o = __shfl(myoff, (int)(e * 16u + t), 64);
                unsigned c = __shfl(mycnt, (int)(e * 16u + t), 64);
                const unsigned long long* sb = rec + segbase + (size_t)t * PPB;
                for (unsigned r = 64u + lane; r < c; r += 64u) {
                    unsigned long long rr = sb[o + r];
                    atomicAdd(&plane[(unsigned)rr & 0x3FFFu],
                              sg * __uint_as_float((unsigned)(rr >> 32)));
                }
            }
        }
    }
    __syncthreads();

    // Reduce diffs out of LDS.
    float tv = 0.f, mse = 0.f;
    if (d1mode) {
#pragma unroll 4
        for (unsigned r = 0; r < 64u; ++r) {
            float d = plane[r * 256u + tid];
            tv += fabsf(d); mse += d * d;
        }
    } else {
#pragma unroll 4
        for (unsigned r = 0; r < 64u; ++r) {
            unsigned v = r * 256u + tid;
            unsigned j = v >> 7, k = v & 127u;
            float c = plane[v];
            if (j < 127u) { float d = plane[v + 128u] - c; tv += fabsf(d); mse += d * d; }
            if (k < 127u) { float d = plane[v + 1u]   - c; tv += fabsf(d); mse += d * d; }
        }
    }

    // Wave shuffle reduce, then cross-wave via plane[0..12).
#pragma unroll
    for (int o = 32; o > 0; o >>= 1) {
        tv  += __shfl_down(tv, o, 64);
        mse += __shfl_down(mse, o, 64);
    }
    __syncthreads();
    if (lane == 0u) { plane[w] = tv; plane[8u + w] = mse; }
    __syncthreads();
    if (tid == 0u) {
        float tt = plane[0] + plane[1] + plane[2] + plane[3];
        float mm = plane[8] + plane[9] + plane[10] + plane[11];
        atomicAdd(stage + (size_t)b * 16u,        tt);
        atomicAdd(stage + (size_t)(8u + b) * 16u, mm);
    }
}

// ---------------------------------------------------------------------------
// Kernel 3: scale staged sums into d_out (overwrites poison).
__global__ void finalize_kernel(const float* __restrict__ stage,
                                float* __restrict__ out) {
    unsigned i = threadIdx.x;
    if (i < 16u) {
        float s = stage[i * 16u];
        float scale = (i < 8u) ? (1.0f / 2097152.0f)     // / 128^3
                               : (1.0f / 32512.0f);      // / (2*128^2 - 2*128)
        out[i] = s * scale;
    }
}

// ---------------------------------------------------------------------------
extern "C" void kernel_launch(void* const* d_in, const int* in_sizes, int n_in,
                              void* d_out, int out_size, void* d_ws, size_t ws_size,
                              hipStream_t stream) {
    const int*   idx  = (const int*)d_in[0];    // [8, 262144, 3] int32
    const float* vals = (const float*)d_in[1];  // [8, 262144] float32

    unsigned long long* rec = (unsigned long long*)d_ws;
    unsigned* tab   = (unsigned*)(rec + REC_U64);
    float*    stage = (float*)(tab + TAB_U32);
    float*    out   = (float*)d_out;

    sort_kernel<<<NSEG, 256, 0, stream>>>(idx, vals, rec, tab, stage);
    accum_kernel<<<2048, 256, 0, stream>>>(rec, tab, stage);
    finalize_kernel<<<1, 64, 0, stream>>>(stage, out);
}

// Round 5
// 145.444 us; speedup vs baseline: 1.5002x; 1.0657x over previous
//
#include <hip/hip_runtime.h>

// Problem constants (fixed by reference: XSIZE=128, B=8, N=262144)
constexpr unsigned XS        = 128;
constexpr unsigned NB        = 8;
constexpr unsigned NPTS      = 262144;           // 2^18 per batch
constexpr unsigned TOTAL_PTS = NB * NPTS;        // 2^21
constexpr unsigned PPB       = 1024;             // points per sort segment
constexpr unsigned NSEG      = TOTAL_PTS / PPB;  // 2048 segments
constexpr unsigned SPB       = NPTS / PPB;       // 256 segments per batch

// d_ws layout:
//   rec  : u64 [TOTAL_PTS]     = 16 MiB  (counting-sorted records)
//   tab  : u32 [XS * NSEG]     = 1 MiB   TRANSPOSED: tab[i*NSEG + seg] = off | cnt<<16
//   stage: f32 [256]           = 1 KiB   (zeroed by sort_kernel block 0)
constexpr size_t REC_U64 = (size_t)TOTAL_PTS;
constexpr size_t TAB_U32 = (size_t)XS * NSEG;

// ---------------------------------------------------------------------------
// Kernel 1: block-local counting sort by i-plane. 2048 blocks (8/CU, 32
// waves/CU). Block g sorts points [g*1024,(g+1)*1024) into segment g grouped
// by i; writes the transposed off/cnt table. Block 0 zeroes stage.
__global__ __launch_bounds__(256) void sort_kernel(
        const int* __restrict__ idx, const float* __restrict__ vals,
        unsigned long long* __restrict__ rec, unsigned* __restrict__ tab,
        float* __restrict__ stage) {
    __shared__ unsigned long long stg[PPB];      // 8 KiB staging
    __shared__ unsigned hist[XS];
    __shared__ unsigned cur[XS];
    unsigned tid  = threadIdx.x;
    unsigned g    = blockIdx.x;
    unsigned base = g * PPB;

    if (g == 0u) stage[tid] = 0.f;               // 256 floats
    if (tid < XS) hist[tid] = 0u;
    __syncthreads();

    // Pass 1: 4 points/thread, histogram i.
    unsigned key[4]; float val[4];
#pragma unroll
    for (unsigned n = 0; n < 4; ++n) {
        unsigned pt = base + n * 256u + tid;
        const int* p = idx + 3ull * pt;
        unsigned i = (unsigned)p[0], j = (unsigned)p[1], k = (unsigned)p[2];
        key[n] = (i << 14) | (j << 7) | k;
        val[n] = vals[pt];
        atomicAdd(&hist[i], 1u);
    }
    __syncthreads();

    // Exclusive scan of hist[128] by wave 0; write transposed table.
    if (tid < 64u) {
        unsigned h0 = hist[tid], h1 = hist[64u + tid];
        unsigned a0 = h0, a1 = h1;
#pragma unroll
        for (unsigned o = 1; o <= 32; o <<= 1) {
            unsigned t0 = __shfl_up(a0, o, 64);
            unsigned t1 = __shfl_up(a1, o, 64);
            if (tid >= o) { a0 += t0; a1 += t1; }
        }
        a1 += __shfl(a0, 63, 64);
        unsigned e0 = a0 - h0, e1 = a1 - h1;
        cur[tid] = e0; cur[64u + tid] = e1;
        tab[(size_t)tid * NSEG + g]         = e0 | (h0 << 16);
        tab[(size_t)(64u + tid) * NSEG + g] = e1 | (h1 << 16);
    }
    __syncthreads();

    // Pass 2: scatter records into LDS staging at sorted positions.
#pragma unroll
    for (unsigned n = 0; n < 4; ++n) {
        unsigned i = key[n] >> 14;
        unsigned pos = atomicAdd(&cur[i], 1u);
        stg[pos] = ((unsigned long long)__float_as_uint(val[n]) << 32)
                 | (unsigned long long)(key[n] & 0x3FFFu);
    }
    __syncthreads();

    // Flush: fully coalesced float4 stores (2 per thread).
    const float4* s4 = (const float4*)stg;
    float4* d4 = (float4*)(rec + (size_t)base);
#pragma unroll
    for (unsigned n = 0; n < 2; ++n) d4[n * 256u + tid] = s4[n * 256u + tid];
}

// ---------------------------------------------------------------------------
// Kernel 2: one block per (b,i), 512 threads, 64 KB LDS plane; 2 resident
// blocks = 16 waves/CU. Each block:
//   build P_i -> d23 reduce -> negate -> add bucket i+1 -> d1 reduce.
// Wave w owns 32 segments; descriptors: lanes 0..31 = bucket i,
// lanes 32..63 = bucket i+1.
__global__ __launch_bounds__(512, 4) void accum_kernel(
        const unsigned long long* __restrict__ rec,
        const unsigned* __restrict__ tab, float* __restrict__ stage) {
    __shared__ float plane[XS * XS];             // 64 KB
    unsigned z = blockIdx.x;                     // 0..1023
    unsigned b = z >> 7, i = z & 127u;
    bool has_d1 = (i < 127u);                    // block-uniform
    unsigned tid = threadIdx.x, lane = tid & 63u, w = tid >> 6;   // w: 0..7

    // Descriptor gather (coalesced: transposed table).
    unsigned segfirst = b * SPB + w * 32u;       // this wave's first segment
    unsigned d = 0u;
    if (lane < 32u)      d = tab[(size_t)i * NSEG + segfirst + lane];
    else if (has_d1)     d = tab[(size_t)(i + 1u) * NSEG + segfirst + (lane - 32u)];
    unsigned doff = d & 0xFFFFu, dcnt = d >> 16;

    // Wave-uniform overflow flag (counts avg 8; >64 is ~never).
    unsigned mx = dcnt;
#pragma unroll
    for (int o = 32; o > 0; o >>= 1) mx = max(mx, __shfl_down(mx, o, 64));
    mx = __shfl(mx, 0, 64);

    // Zero the plane (8 float4/thread).
    float4* p4 = (float4*)plane;
#pragma unroll
    for (unsigned r = 0; r < 8u; ++r)
        p4[r * 512u + tid] = float4{0.f, 0.f, 0.f, 0.f};
    __syncthreads();

    const unsigned long long* segrec = rec + (size_t)segfirst * PPB;

    // Accumulate 32 segments of one bucket; dbase = descriptor lane base.
    auto phase = [&](unsigned dbase) {
#pragma unroll 2
        for (unsigned c = 0; c < 8u; ++c) {      // chunks of 4 segments
            unsigned long long rv[4]; bool av[4];
#pragma unroll
            for (unsigned q = 0; q < 4u; ++q) {
                unsigned s  = c * 4u + q;
                unsigned o  = __shfl(doff, (int)(dbase + s), 64);
                unsigned cc = __shfl(dcnt, (int)(dbase + s), 64);
                av[q] = lane < cc;
                if (av[q]) rv[q] = segrec[(size_t)s * PPB + o + lane];
            }
#pragma unroll
            for (unsigned q = 0; q < 4u; ++q)
                if (av[q])
                    atomicAdd(&plane[(unsigned)rv[q] & 0x3FFFu],
                              __uint_as_float((unsigned)(rv[q] >> 32)));
        }
        if (mx > 64u) {                          // rare fallback
            for (unsigned s = 0; s < 32u; ++s) {
                unsigned o  = __shfl(doff, (int)(dbase + s), 64);
                unsigned cc = __shfl(dcnt, (int)(dbase + s), 64);
                const unsigned long long* sb = segrec + (size_t)s * PPB;
                for (unsigned r = 64u + lane; r < cc; r += 64u) {
                    unsigned long long rr = sb[o + r];
                    atomicAdd(&plane[(unsigned)rr & 0x3FFFu],
                              __uint_as_float((unsigned)(rr >> 32)));
                }
            }
        }
    };

    // Phase A: plane = P_i.
    phase(0u);
    __syncthreads();

    // d23 reduce from P_i (32 iters/thread).
    float tv = 0.f, mse = 0.f;
#pragma unroll 4
    for (unsigned r = 0; r < 32u; ++r) {
        unsigned v = r * 512u + tid;
        unsigned j = v >> 7, k = v & 127u;
        float c = plane[v];
        if (j < 127u) { float dd = plane[v + 128u] - c; tv += fabsf(dd); mse += dd * dd; }
        if (k < 127u) { float dd = plane[v + 1u]   - c; tv += fabsf(dd); mse += dd * dd; }
    }

    if (has_d1) {
        __syncthreads();                         // reads of P_i done
        // Negate: plane = -P_i (8 float4/thread).
#pragma unroll
        for (unsigned r = 0; r < 8u; ++r) {
            float4 t = p4[r * 512u + tid];
            p4[r * 512u + tid] = float4{-t.x, -t.y, -t.z, -t.w};
        }
        __syncthreads();
        // Phase B: plane = P_{i+1} - P_i.
        phase(32u);
        __syncthreads();
        // d1 reduce.
#pragma unroll 4
        for (unsigned r = 0; r < 32u; ++r) {
            float dd = plane[r * 512u + tid];
            tv += fabsf(dd); mse += dd * dd;
        }
    }

    // Block reduction: wave shuffle, then cross-wave via plane[0..16).
#pragma unroll
    for (int o = 32; o > 0; o >>= 1) {
        tv  += __shfl_down(tv, o, 64);
        mse += __shfl_down(mse, o, 64);
    }
    __syncthreads();                             // all plane reads done
    if (lane == 0u) { plane[w] = tv; plane[8u + w] = mse; }
    __syncthreads();
    if (tid == 0u) {
        float tt = 0.f, mm = 0.f;
#pragma unroll
        for (unsigned q = 0; q < 8u; ++q) { tt += plane[q]; mm += plane[8u + q]; }
        atomicAdd(stage + (size_t)b * 16u,        tt);
        atomicAdd(stage + (size_t)(8u + b) * 16u, mm);
    }
}

// ---------------------------------------------------------------------------
// Kernel 3: scale staged sums into d_out (overwrites poison).
__global__ void finalize_kernel(const float* __restrict__ stage,
                                float* __restrict__ out) {
    unsigned i = threadIdx.x;
    if (i < 16u) {
        float s = stage[i * 16u];
        float scale = (i < 8u) ? (1.0f / 2097152.0f)     // / 128^3
                               : (1.0f / 32512.0f);      // / (2*128^2 - 2*128)
        out[i] = s * scale;
    }
}

// ---------------------------------------------------------------------------
extern "C" void kernel_launch(void* const* d_in, const int* in_sizes, int n_in,
                              void* d_out, int out_size, void* d_ws, size_t ws_size,
                              hipStream_t stream) {
    const int*   idx  = (const int*)d_in[0];    // [8, 262144, 3] int32
    const float* vals = (const float*)d_in[1];  // [8, 262144] float32

    unsigned long long* rec = (unsigned long long*)d_ws;
    unsigned* tab   = (unsigned*)(rec + REC_U64);
    float*    stage = (float*)(tab + TAB_U32);
    float*    out   = (float*)d_out;

    sort_kernel<<<NSEG, 256, 0, stream>>>(idx, vals, rec, tab, stage);
    accum_kernel<<<NB * XS, 512, 0, stream>>>(rec, tab, stage);
    finalize_kernel<<<1, 64, 0, stream>>>(stage, out);
}

// Round 6
// 125.820 us; speedup vs baseline: 1.7342x; 1.1560x over previous
//
#include <hip/hip_runtime.h>

// Problem constants (fixed by reference: XSIZE=128, B=8, N=262144)
constexpr unsigned XS        = 128;
constexpr unsigned NB        = 8;
constexpr unsigned NPTS      = 262144;           // 2^18 per batch
constexpr unsigned TOTAL_PTS = NB * NPTS;        // 2^21
constexpr unsigned PPB       = 1024;             // points per bin block
constexpr unsigned NSEG      = TOTAL_PTS / PPB;  // 2048 blocks
constexpr unsigned NBKT      = NB * XS;          // 1024 buckets (b,i)
constexpr unsigned CAP       = 3072;             // records per bucket; mean 2048, +22 sigma

// d_ws layout:
//   rec2 : u64 [NBKT*CAP] = 24 MiB  (bucket-dense records)
//   gcur : u32 [1024]     = 4 KiB   (bucket cursors, memset 0)
//   stage: f32 [256]      = 1 KiB   (memset 0)
constexpr size_t REC2_U64 = (size_t)NBKT * CAP;

// ---------------------------------------------------------------------------
// Kernel 1: bin points by (b,i) into dense global bucket regions.
// 2048 blocks x 256 thr, 1024 points each. Record = [val:32 | key21:32].
__global__ __launch_bounds__(256) void bin_kernel(
        const int* __restrict__ idx, const float* __restrict__ vals,
        unsigned long long* __restrict__ rec2, unsigned* __restrict__ gcur) {
    __shared__ unsigned long long sbuf[PPB + PPB / 2];   // 12 KiB: idx stage / rec stage
    __shared__ unsigned hist[XS], cur[XS], loff[XS], gbase[XS];
    unsigned tid = threadIdx.x, g = blockIdx.x;
    unsigned b = g >> 8;                         // 256 blocks per batch
    unsigned base = g * PPB;

    // Stage idx into LDS with perfect uint4 coalescing (768 uint4 = 3072 u32).
    {
        const uint4* src = (const uint4*)idx + (size_t)g * (PPB * 3u / 4u);
        uint4* dst = (uint4*)sbuf;
#pragma unroll
        for (unsigned n = 0; n < 3u; ++n) dst[n * 256u + tid] = src[n * 256u + tid];
    }
    if (tid < XS) hist[tid] = 0u;
    __syncthreads();

    // Pass 1: keys from LDS (stride-3 -> conflict-free), vals coalesced; hist i.
    const unsigned* ibuf = (const unsigned*)sbuf;
    unsigned key[4]; float val[4];
#pragma unroll
    for (unsigned n = 0; n < 4u; ++n) {
        unsigned p = n * 256u + tid;             // local point id
        unsigned i = ibuf[3u * p], j = ibuf[3u * p + 1u], k = ibuf[3u * p + 2u];
        key[n] = (i << 14) | (j << 7) | k;
        val[n] = vals[base + p];
        atomicAdd(&hist[i], 1u);
    }
    __syncthreads();                             // ibuf reads + hist done

    // Exclusive scan of hist[128] by wave 0.
    if (tid < 64u) {
        unsigned h0 = hist[tid], h1 = hist[64u + tid];
        unsigned a0 = h0, a1 = h1;
#pragma unroll
        for (unsigned o = 1; o <= 32; o <<= 1) {
            unsigned t0 = __shfl_up(a0, o, 64);
            unsigned t1 = __shfl_up(a1, o, 64);
            if (tid >= o) { a0 += t0; a1 += t1; }
        }
        a1 += __shfl(a0, 63, 64);
        unsigned e0 = a0 - h0, e1 = a1 - h1;
        loff[tid] = e0; loff[64u + tid] = e1;
        cur[tid]  = e0; cur[64u + tid]  = e1;
    }
    __syncthreads();

    // Pass 2: scatter records into LDS (reusing sbuf as u64[1024]) at sorted
    // positions; concurrently reserve dense global space per bin.
    if (tid < XS) gbase[tid] = atomicAdd(&gcur[b * XS + tid], hist[tid]);
#pragma unroll
    for (unsigned n = 0; n < 4u; ++n) {
        unsigned i = key[n] >> 14;
        unsigned pos = atomicAdd(&cur[i], 1u);
        sbuf[pos] = ((unsigned long long)__float_as_uint(val[n]) << 32)
                  | (unsigned long long)key[n];
    }
    __syncthreads();

    // Write-out: records go dense into their bucket region (runs of ~8).
#pragma unroll
    for (unsigned n = 0; n < 4u; ++n) {
        unsigned s = n * 256u + tid;
        unsigned long long rr = sbuf[s];
        unsigned bin = ((unsigned)rr >> 14) & 127u;
        unsigned dst = gbase[bin] + (s - loff[bin]);
        if (dst < CAP)
            rec2[(size_t)(b * XS + bin) * CAP + dst] = rr;
    }
}

// ---------------------------------------------------------------------------
// Kernel 2: one block per (b,i), 512 thr, 64 KB LDS plane (2 blocks/CU).
// Bucket records are DENSE: all loads + LDS atomics run full-lane.
//   build P_i -> d23 reduce -> negate -> add bucket i+1 -> d1 reduce.
__global__ __launch_bounds__(512, 4) void accum_kernel(
        const unsigned long long* __restrict__ rec2,
        const unsigned* __restrict__ gcur, float* __restrict__ stage) {
    __shared__ float plane[XS * XS];             // 64 KB
    unsigned z = blockIdx.x;                     // 0..1023
    unsigned b = z >> 7, i = z & 127u;
    bool has_d1 = (i < 127u);
    unsigned tid = threadIdx.x, lane = tid & 63u, w = tid >> 6;

    unsigned cnt0 = min(gcur[b * XS + i], CAP);
    unsigned cnt1 = has_d1 ? min(gcur[b * XS + i + 1u], CAP) : 0u;

    // Zero the plane (8 float4/thread).
    float4* p4 = (float4*)plane;
#pragma unroll
    for (unsigned r = 0; r < 8u; ++r)
        p4[r * 512u + tid] = float4{0.f, 0.f, 0.f, 0.f};
    __syncthreads();

    // Accumulate one dense bucket: <=6 predicated full-lane chunks.
    auto phase = [&](const unsigned long long* __restrict__ bkt, unsigned cnt) {
        unsigned long long rv[6]; bool av[6];
#pragma unroll
        for (unsigned q = 0; q < 6u; ++q) {
            unsigned r = q * 512u + tid;
            av[q] = r < cnt;
            if (av[q]) rv[q] = bkt[r];
        }
#pragma unroll
        for (unsigned q = 0; q < 6u; ++q)
            if (av[q])
                atomicAdd(&plane[(unsigned)rv[q] & 0x3FFFu],
                          __uint_as_float((unsigned)(rv[q] >> 32)));
    };

    // Phase A: plane = P_i.
    phase(rec2 + (size_t)(b * XS + i) * CAP, cnt0);
    __syncthreads();

    // d23 reduce from P_i (32 iters/thread).
    float tv = 0.f, mse = 0.f;
#pragma unroll 4
    for (unsigned r = 0; r < 32u; ++r) {
        unsigned v = r * 512u + tid;
        unsigned j = v >> 7, k = v & 127u;
        float c = plane[v];
        if (j < 127u) { float dd = plane[v + 128u] - c; tv += fabsf(dd); mse += dd * dd; }
        if (k < 127u) { float dd = plane[v + 1u]   - c; tv += fabsf(dd); mse += dd * dd; }
    }

    if (has_d1) {
        __syncthreads();                         // P_i reads done
#pragma unroll
        for (unsigned r = 0; r < 8u; ++r) {      // plane = -P_i
            float4 t = p4[r * 512u + tid];
            p4[r * 512u + tid] = float4{-t.x, -t.y, -t.z, -t.w};
        }
        __syncthreads();
        // Phase B: plane = P_{i+1} - P_i.
        phase(rec2 + (size_t)(b * XS + i + 1u) * CAP, cnt1);
        __syncthreads();
        // d1 reduce.
#pragma unroll 4
        for (unsigned r = 0; r < 32u; ++r) {
            float dd = plane[r * 512u + tid];
            tv += fabsf(dd); mse += dd * dd;
        }
    }

    // Block reduction: wave shuffle, then cross-wave via plane[0..16).
#pragma unroll
    for (int o = 32; o > 0; o >>= 1) {
        tv  += __shfl_down(tv, o, 64);
        mse += __shfl_down(mse, o, 64);
    }
    __syncthreads();
    if (lane == 0u) { plane[w] = tv; plane[8u + w] = mse; }
    __syncthreads();
    if (tid == 0u) {
        float tt = 0.f, mm = 0.f;
#pragma unroll
        for (unsigned q = 0; q < 8u; ++q) { tt += plane[q]; mm += plane[8u + q]; }
        atomicAdd(stage + (size_t)b * 16u,        tt);
        atomicAdd(stage + (size_t)(8u + b) * 16u, mm);
    }
}

// ---------------------------------------------------------------------------
// Kernel 3: scale staged sums into d_out (overwrites poison).
__global__ void finalize_kernel(const float* __restrict__ stage,
                                float* __restrict__ out) {
    unsigned i = threadIdx.x;
    if (i < 16u) {
        float s = stage[i * 16u];
        float scale = (i < 8u) ? (1.0f / 2097152.0f)     // / 128^3
                               : (1.0f / 32512.0f);      // / (2*128^2 - 2*128)
        out[i] = s * scale;
    }
}

// ---------------------------------------------------------------------------
extern "C" void kernel_launch(void* const* d_in, const int* in_sizes, int n_in,
                              void* d_out, int out_size, void* d_ws, size_t ws_size,
                              hipStream_t stream) {
    const int*   idx  = (const int*)d_in[0];    // [8, 262144, 3] int32
    const float* vals = (const float*)d_in[1];  // [8, 262144] float32

    unsigned long long* rec2 = (unsigned long long*)d_ws;
    unsigned* gcur  = (unsigned*)(rec2 + REC2_U64);
    float*    stage = (float*)(gcur + NBKT);
    float*    out   = (float*)d_out;

    // Zero cursors (4 KiB) + stage (1 KiB) in one tiny memset.
    hipMemsetAsync(gcur, 0, NBKT * 4 + 256 * 4, stream);

    bin_kernel<<<NSEG, 256, 0, stream>>>(idx, vals, rec2, gcur);
    accum_kernel<<<NBKT, 512, 0, stream>>>(rec2, gcur, stage);
    finalize_kernel<<<1, 64, 0, stream>>>(stage, out);
}

// Round 7
// 124.600 us; speedup vs baseline: 1.7512x; 1.0098x over previous
//
#include <hip/hip_runtime.h>

// Problem constants (fixed by reference: XSIZE=128, B=8, N=262144)
constexpr unsigned XS        = 128;
constexpr unsigned NB        = 8;
constexpr unsigned NPTS      = 262144;           // 2^18 per batch
constexpr unsigned TOTAL_PTS = NB * NPTS;        // 2^21
constexpr unsigned PPB       = 1024;             // points per bin block
constexpr unsigned NSEG      = TOTAL_PTS / PPB;  // 2048 blocks
constexpr unsigned NBKT      = NB * XS;          // 1024 buckets (b,i)
constexpr unsigned CAP       = 3072;             // records/bucket; mean 2048, +22 sigma

// d_ws layout:
//   rec2 : u64 [NBKT*CAP] = 24 MiB  (bucket-dense records)
//   gcur : u32 [1024]     = 4 KiB   (bucket cursors, memset 0)
//   stage: f32 [256]      = 1 KiB   (memset 0)
constexpr size_t REC2_U64 = (size_t)NBKT * CAP;

// ---------------------------------------------------------------------------
// Kernel 1: bin points by (b,i) into dense global bucket regions.
// 2048 blocks x 256 thr, 1024 points each. Record = [val:32 | key21:32].
__global__ __launch_bounds__(256) void bin_kernel(
        const int* __restrict__ idx, const float* __restrict__ vals,
        unsigned long long* __restrict__ rec2, unsigned* __restrict__ gcur) {
    __shared__ unsigned long long sbuf[PPB + PPB / 2];   // 12 KiB
    __shared__ unsigned hist[XS], cur[XS], loff[XS], gbase[XS];
    unsigned tid = threadIdx.x, g = blockIdx.x;
    unsigned b = g >> 8;                         // 256 blocks per batch
    unsigned base = g * PPB;

    // Stage idx into LDS with perfect uint4 coalescing (768 uint4).
    {
        const uint4* src = (const uint4*)idx + (size_t)g * (PPB * 3u / 4u);
        uint4* dst = (uint4*)sbuf;
#pragma unroll
        for (unsigned n = 0; n < 3u; ++n) dst[n * 256u + tid] = src[n * 256u + tid];
    }
    if (tid < XS) hist[tid] = 0u;
    __syncthreads();

    // Pass 1: keys from LDS (stride-3 -> conflict-free), vals coalesced.
    const unsigned* ibuf = (const unsigned*)sbuf;
    unsigned key[4]; float val[4];
#pragma unroll
    for (unsigned n = 0; n < 4u; ++n) {
        unsigned p = n * 256u + tid;
        unsigned i = ibuf[3u * p], j = ibuf[3u * p + 1u], k = ibuf[3u * p + 2u];
        key[n] = (i << 14) | (j << 7) | k;
        val[n] = vals[base + p];
        atomicAdd(&hist[i], 1u);
    }
    __syncthreads();

    // Exclusive scan of hist[128] by wave 0.
    if (tid < 64u) {
        unsigned h0 = hist[tid], h1 = hist[64u + tid];
        unsigned a0 = h0, a1 = h1;
#pragma unroll
        for (unsigned o = 1; o <= 32; o <<= 1) {
            unsigned t0 = __shfl_up(a0, o, 64);
            unsigned t1 = __shfl_up(a1, o, 64);
            if (tid >= o) { a0 += t0; a1 += t1; }
        }
        a1 += __shfl(a0, 63, 64);
        unsigned e0 = a0 - h0, e1 = a1 - h1;
        loff[tid] = e0; loff[64u + tid] = e1;
        cur[tid]  = e0; cur[64u + tid]  = e1;
    }
    __syncthreads();

    // Pass 2: scatter records into LDS at sorted positions; reserve global.
    if (tid < XS) gbase[tid] = atomicAdd(&gcur[b * XS + tid], hist[tid]);
#pragma unroll
    for (unsigned n = 0; n < 4u; ++n) {
        unsigned i = key[n] >> 14;
        unsigned pos = atomicAdd(&cur[i], 1u);
        sbuf[pos] = ((unsigned long long)__float_as_uint(val[n]) << 32)
                  | (unsigned long long)key[n];
    }
    __syncthreads();

    // Write-out: dense runs (~8 records) into each bucket region.
#pragma unroll
    for (unsigned n = 0; n < 4u; ++n) {
        unsigned s = n * 256u + tid;
        unsigned long long rr = sbuf[s];
        unsigned bin = ((unsigned)rr >> 14) & 127u;
        unsigned dst = gbase[bin] + (s - loff[bin]);
        if (dst < CAP)
            rec2[(size_t)(b * XS + bin) * CAP + dst] = rr;
    }
}

// ---------------------------------------------------------------------------
// Kernel 2: one block per (b,i), 512 thr, 64 KB LDS plane (2 blocks/CU).
//   issue A-loads -> zero plane -> A-atomics(+v) -> [issue B-loads]
//   -> d23 reduce (float4) -> B-atomics(-v) -> d1 reduce (float4).
// plane after B = P_i - P_{i+1}: |.| and (.)^2 are even, so no negate needed.
__global__ __launch_bounds__(512, 4) void accum_kernel(
        const unsigned long long* __restrict__ rec2,
        const unsigned* __restrict__ gcur, float* __restrict__ stage) {
    __shared__ float plane[XS * XS];             // 64 KB
    unsigned z = blockIdx.x;                     // 0..1023
    unsigned b = z >> 7, i = z & 127u;
    bool has_d1 = (i < 127u);
    unsigned tid = threadIdx.x, lane = tid & 63u, w = tid >> 6;

    unsigned cnt0 = min(gcur[b * XS + i], CAP);
    unsigned cnt1 = has_d1 ? min(gcur[b * XS + i + 1u], CAP) : 0u;

    const unsigned long long* bktA = rec2 + (size_t)(b * XS + i) * CAP;
    const unsigned long long* bktB = bktA + CAP;

    // Issue phase-A loads first (latency hides under plane zeroing).
    unsigned long long rvA[6]; bool avA[6];
#pragma unroll
    for (unsigned q = 0; q < 6u; ++q) {
        unsigned r = q * 512u + tid;
        avA[q] = r < cnt0;
        if (avA[q]) rvA[q] = bktA[r];
    }

    // Zero the plane (8 float4/thread).
    float4* p4 = (float4*)plane;
#pragma unroll
    for (unsigned r = 0; r < 8u; ++r)
        p4[r * 512u + tid] = float4{0.f, 0.f, 0.f, 0.f};
    __syncthreads();

    // Phase A atomics: plane = P_i.
#pragma unroll
    for (unsigned q = 0; q < 6u; ++q)
        if (avA[q])
            atomicAdd(&plane[(unsigned)rvA[q] & 0x3FFFu],
                      __uint_as_float((unsigned)(rvA[q] >> 32)));
    __syncthreads();

    // Issue phase-B loads NOW: independent of plane; latency hides under
    // the d23 reduce below.
    unsigned long long rvB[6]; bool avB[6];
    if (has_d1) {
#pragma unroll
        for (unsigned q = 0; q < 6u; ++q) {
            unsigned r = q * 512u + tid;
            avB[q] = r < cnt1;
            if (avB[q]) rvB[q] = bktB[r];
        }
    }

    // d23 reduce from P_i, float4-wide: 8 chunks of 4 voxels per thread.
    float tv = 0.f, mse = 0.f;
#pragma unroll
    for (unsigned r = 0; r < 8u; ++r) {
        unsigned v4 = r * 512u + tid;            // float4 index, 0..4095
        unsigned j = v4 >> 5, k4 = v4 & 31u;
        float4 c = p4[v4];
        float d0 = c.y - c.x, d1 = c.z - c.y, d2 = c.w - c.z;
        tv  += fabsf(d0) + fabsf(d1) + fabsf(d2);
        mse += d0 * d0 + d1 * d1 + d2 * d2;
        if (k4 < 31u) {                          // k-seam to next chunk
            float nx = plane[4u * v4 + 4u];
            float d3 = nx - c.w;
            tv += fabsf(d3); mse += d3 * d3;
        }
        if (j < 127u) {                          // j-neighbor row
            float4 n = p4[v4 + 32u];
            float e0 = n.x - c.x, e1 = n.y - c.y, e2 = n.z - c.z, e3 = n.w - c.w;
            tv  += fabsf(e0) + fabsf(e1) + fabsf(e2) + fabsf(e3);
            mse += e0 * e0 + e1 * e1 + e2 * e2 + e3 * e3;
        }
    }

    if (has_d1) {
        __syncthreads();                         // all P_i reads done
        // Phase B atomics with sign -1: plane = P_i - P_{i+1}.
#pragma unroll
        for (unsigned q = 0; q < 6u; ++q)
            if (avB[q])
                atomicAdd(&plane[(unsigned)rvB[q] & 0x3FFFu],
                          -__uint_as_float((unsigned)(rvB[q] >> 32)));
        __syncthreads();
        // d1 reduce, float4-wide.
#pragma unroll
        for (unsigned r = 0; r < 8u; ++r) {
            float4 dd = p4[r * 512u + tid];
            tv  += fabsf(dd.x) + fabsf(dd.y) + fabsf(dd.z) + fabsf(dd.w);
            mse += dd.x * dd.x + dd.y * dd.y + dd.z * dd.z + dd.w * dd.w;
        }
    }

    // Block reduction: wave shuffle, then cross-wave via plane[0..16).
#pragma unroll
    for (int o = 32; o > 0; o >>= 1) {
        tv  += __shfl_down(tv, o, 64);
        mse += __shfl_down(mse, o, 64);
    }
    __syncthreads();                             // plane reads done
    if (lane == 0u) { plane[w] = tv; plane[8u + w] = mse; }
    __syncthreads();
    if (tid == 0u) {
        float tt = 0.f, mm = 0.f;
#pragma unroll
        for (unsigned q = 0; q < 8u; ++q) { tt += plane[q]; mm += plane[8u + q]; }
        atomicAdd(stage + (size_t)b * 16u,        tt);
        atomicAdd(stage + (size_t)(8u + b) * 16u, mm);
    }
}

// ---------------------------------------------------------------------------
// Kernel 3: scale staged sums into d_out (overwrites poison).
__global__ void finalize_kernel(const float* __restrict__ stage,
                                float* __restrict__ out) {
    unsigned i = threadIdx.x;
    if (i < 16u) {
        float s = stage[i * 16u];
        float scale = (i < 8u) ? (1.0f / 2097152.0f)     // / 128^3
                               : (1.0f / 32512.0f);      // / (2*128^2 - 2*128)
        out[i] = s * scale;
    }
}

// ---------------------------------------------------------------------------
extern "C" void kernel_launch(void* const* d_in, const int* in_sizes, int n_in,
                              void* d_out, int out_size, void* d_ws, size_t ws_size,
                              hipStream_t stream) {
    const int*   idx  = (const int*)d_in[0];    // [8, 262144, 3] int32
    const float* vals = (const float*)d_in[1];  // [8, 262144] float32

    unsigned long long* rec2 = (unsigned long long*)d_ws;
    unsigned* gcur  = (unsigned*)(rec2 + REC2_U64);
    float*    stage = (float*)(gcur + NBKT);
    float*    out   = (float*)d_out;

    // Zero cursors (4 KiB) + stage (1 KiB).
    hipMemsetAsync(gcur, 0, NBKT * 4 + 256 * 4, stream);

    bin_kernel<<<NSEG, 256, 0, stream>>>(idx, vals, rec2, gcur);
    accum_kernel<<<NBKT, 512, 0, stream>>>(rec2, gcur, stage);
    finalize_kernel<<<1, 64, 0, stream>>>(stage, out);
}

// Round 8
// 115.654 us; speedup vs baseline: 1.8867x; 1.0774x over previous
//
#include <hip/hip_runtime.h>

// Problem constants (fixed by reference: XSIZE=128, B=8, N=262144)
constexpr unsigned XS        = 128;
constexpr unsigned NB        = 8;
constexpr unsigned NPTS      = 262144;           // 2^18 per batch
constexpr unsigned TOTAL_PTS = NB * NPTS;        // 2^21
constexpr unsigned PPB       = 4096;             // points per bin block
constexpr unsigned NSEG      = TOTAL_PTS / PPB;  // 512 bin blocks (64/batch)
constexpr unsigned NBKT      = NB * XS;          // 1024 buckets (b,i)
constexpr unsigned CAP       = 3072;             // records/bucket; mean 2048, +22 sigma

// d_ws layout:
//   rec2 : u64 [NBKT*CAP] = 24 MiB  (bucket-dense records)
//   gcur : u32 [1024]     = 4 KiB   (bucket cursors, memset 0)
//   stage: f32 [256]      = 1 KiB   (memset 0)
constexpr size_t REC2_U64 = (size_t)NBKT * CAP;

// ---------------------------------------------------------------------------
// Kernel 1: bin points by (b,i) into dense global bucket regions.
// 512 blocks x 256 thr, 4096 points each -> write runs of ~32 recs (256 B).
// Record = [val:32 | key21:32]. idx staged through LDS in 4 rounds (12 KiB
// chunk) unioned with the 32 KiB record-staging buffer.
__global__ __launch_bounds__(256) void bin_kernel(
        const int* __restrict__ idx, const float* __restrict__ vals,
        unsigned long long* __restrict__ rec2, unsigned* __restrict__ gcur) {
    __shared__ unsigned long long sbuf[PPB];     // 32 KiB (idx chunks alias low 12 KiB)
    __shared__ unsigned hist[XS], cur[XS], loff[XS], gbase[XS];
    unsigned tid = threadIdx.x, g = blockIdx.x;
    unsigned b = g >> 6;                         // 64 blocks per batch
    unsigned base = g * PPB;

    if (tid < XS) hist[tid] = 0u;

    // 4 rounds: stage 1024 points' idx (3072 u32 = 768 uint4) into LDS,
    // extract keys to registers, histogram i; vals loaded coalesced.
    unsigned key[16]; float val[16];
    const unsigned* ibuf = (const unsigned*)sbuf;
    for (unsigned r = 0; r < 4u; ++r) {
        __syncthreads();                         // prev round's reads done
        {
            const uint4* src = (const uint4*)idx + ((size_t)g * 3072u + r * 768u);
            uint4* dst = (uint4*)sbuf;
#pragma unroll
            for (unsigned n = 0; n < 3u; ++n) dst[n * 256u + tid] = src[n * 256u + tid];
        }
        __syncthreads();
#pragma unroll
        for (unsigned n = 0; n < 4u; ++n) {
            unsigned p = n * 256u + tid;         // local point in chunk
            unsigned i = ibuf[3u * p], j = ibuf[3u * p + 1u], k = ibuf[3u * p + 2u];
            unsigned m = r * 4u + n;
            key[m] = (i << 14) | (j << 7) | k;
            val[m] = vals[base + r * 1024u + p];
            atomicAdd(&hist[i], 1u);
        }
    }
    __syncthreads();

    // Exclusive scan of hist[128] by wave 0; reserve dense global space.
    if (tid < 64u) {
        unsigned h0 = hist[tid], h1 = hist[64u + tid];
        unsigned a0 = h0, a1 = h1;
#pragma unroll
        for (unsigned o = 1; o <= 32; o <<= 1) {
            unsigned t0 = __shfl_up(a0, o, 64);
            unsigned t1 = __shfl_up(a1, o, 64);
            if (tid >= o) { a0 += t0; a1 += t1; }
        }
        a1 += __shfl(a0, 63, 64);
        unsigned e0 = a0 - h0, e1 = a1 - h1;
        loff[tid] = e0; loff[64u + tid] = e1;
        cur[tid]  = e0; cur[64u + tid]  = e1;
    }
    __syncthreads();
    if (tid < XS) gbase[tid] = atomicAdd(&gcur[b * XS + tid], hist[tid]);

    // Scatter records into LDS at sorted positions (idx region now dead).
#pragma unroll
    for (unsigned m = 0; m < 16u; ++m) {
        unsigned i = key[m] >> 14;
        unsigned pos = atomicAdd(&cur[i], 1u);
        sbuf[pos] = ((unsigned long long)__float_as_uint(val[m]) << 32)
                  | (unsigned long long)key[m];
    }
    __syncthreads();

    // Write-out: dense runs (~32 recs = 256 B) into bucket regions.
#pragma unroll
    for (unsigned m = 0; m < 16u; ++m) {
        unsigned s = m * 256u + tid;
        unsigned long long rr = sbuf[s];
        unsigned bin = ((unsigned)rr >> 14) & 127u;
        unsigned dst = gbase[bin] + (s - loff[bin]);
        if (dst < CAP)
            rec2[(size_t)(b * XS + bin) * CAP + dst] = rr;
    }
}

// ---------------------------------------------------------------------------
// Kernel 2: one block per (b, i, j-half), 512 thr, 65x128 LDS strip (33 KB)
// -> ~4 blocks/CU (~32 waves). Reads full (b,i)/(b,i+1) buckets, filters by j.
//   A: strip = P_i rows [j0, j0+64]  (65 rows incl seam; s=1 has 64)
//   d23 reduce on owned rows [j0, j0+63] (j-pairs use seam row)
//   B: strip -= P_{i+1} on owned rows only -> d1 reduce on owned rows.
__global__ __launch_bounds__(512) void accum_kernel(
        const unsigned long long* __restrict__ rec2,
        const unsigned* __restrict__ gcur, float* __restrict__ stage) {
    __shared__ float strip[65u * XS];            // 33,280 B
    __shared__ float sred[16];
    unsigned z = blockIdx.x;                     // 0..2047
    unsigned b = z >> 8, i = (z >> 1) & 127u, h = z & 1u;
    unsigned j0 = h << 6;                        // 0 or 64
    bool has_d1 = (i < 127u);
    unsigned tid = threadIdx.x, lane = tid & 63u, w = tid >> 6;

    unsigned cnt0 = min(gcur[b * XS + i], CAP);
    unsigned cnt1 = has_d1 ? min(gcur[b * XS + i + 1u], CAP) : 0u;
    const unsigned long long* bktA = rec2 + (size_t)(b * XS + i) * CAP;
    const unsigned long long* bktB = bktA + CAP;

    // Issue phase-A loads (latency hides under strip zeroing).
    unsigned long long rvA[6]; bool avA[6];
#pragma unroll
    for (unsigned q = 0; q < 6u; ++q) {
        unsigned r = q * 512u + tid;
        avA[q] = r < cnt0;
        if (avA[q]) rvA[q] = bktA[r];
    }

    // Zero the strip (8320 floats = 2080 float4).
    float4* p4 = (float4*)strip;
    for (unsigned r = tid; r < 2080u; r += 512u)
        p4[r] = float4{0.f, 0.f, 0.f, 0.f};
    __syncthreads();

    // Phase A atomics: accept j in [j0, j0+64].
#pragma unroll
    for (unsigned q = 0; q < 6u; ++q)
        if (avA[q]) {
            unsigned kk = (unsigned)rvA[q];
            unsigned j = (kk >> 7) & 127u;
            unsigned l = j - j0;                 // local row (wraps if j<j0)
            if (l <= 64u)
                atomicAdd(&strip[(l << 7) | (kk & 127u)],
                          __uint_as_float((unsigned)(rvA[q] >> 32)));
        }
    __syncthreads();

    // Issue phase-B loads now; latency hides under the d23 reduce.
    unsigned long long rvB[6]; bool avB[6];
    if (has_d1) {
#pragma unroll
        for (unsigned q = 0; q < 6u; ++q) {
            unsigned r = q * 512u + tid;
            avB[q] = r < cnt1;
            if (avB[q]) rvB[q] = bktB[r];
        }
    }

    // d23 reduce over owned rows: 16 voxels = 4 float4 per thread.
    unsigned jmax = 127u - j0;                   // j-pair valid iff l < jmax
    float tv = 0.f, mse = 0.f;
#pragma unroll
    for (unsigned r = 0; r < 4u; ++r) {
        unsigned v4 = r * 512u + tid;            // float4 idx in [0, 2048) = rows [0,64)
        unsigned l = v4 >> 5, k4 = v4 & 31u;
        float4 c = p4[v4];
        float d0 = c.y - c.x, d1 = c.z - c.y, d2 = c.w - c.z;
        tv  += fabsf(d0) + fabsf(d1) + fabsf(d2);
        mse += d0 * d0 + d1 * d1 + d2 * d2;
        if (k4 < 31u) {                          // k-seam within row
            float nx = strip[(v4 << 2) + 4u];
            float d3 = nx - c.w;
            tv += fabsf(d3); mse += d3 * d3;
        }
        if (l < jmax) {                          // j-pair (uses seam row at l=63)
            float4 n = p4[v4 + 32u];
            float e0 = n.x - c.x, e1 = n.y - c.y, e2 = n.z - c.z, e3 = n.w - c.w;
            tv  += fabsf(e0) + fabsf(e1) + fabsf(e2) + fabsf(e3);
            mse += e0 * e0 + e1 * e1 + e2 * e2 + e3 * e3;
        }
    }

    if (has_d1) {
        __syncthreads();                         // P_i reads done
        // Phase B atomics (sign -1): owned rows only -> strip = P_i - P_{i+1}.
#pragma unroll
        for (unsigned q = 0; q < 6u; ++q)
            if (avB[q]) {
                unsigned kk = (unsigned)rvB[q];
                unsigned j = (kk >> 7) & 127u;
                unsigned l = j - j0;
                if (l <= 63u)
                    atomicAdd(&strip[(l << 7) | (kk & 127u)],
                              -__uint_as_float((unsigned)(rvB[q] >> 32)));
            }
        __syncthreads();
        // d1 reduce over owned rows (|.| and (.)^2 are even: sign irrelevant).
#pragma unroll
        for (unsigned r = 0; r < 4u; ++r) {
            float4 dd = p4[r * 512u + tid];
            tv  += fabsf(dd.x) + fabsf(dd.y) + fabsf(dd.z) + fabsf(dd.w);
            mse += dd.x * dd.x + dd.y * dd.y + dd.z * dd.z + dd.w * dd.w;
        }
    }

    // Block reduction: wave shuffle, then cross-wave via sred.
#pragma unroll
    for (int o = 32; o > 0; o >>= 1) {
        tv  += __shfl_down(tv, o, 64);
        mse += __shfl_down(mse, o, 64);
    }
    if (lane == 0u) { sred[w] = tv; sred[8u + w] = mse; }
    __syncthreads();
    if (tid == 0u) {
        float tt = 0.f, mm = 0.f;
#pragma unroll
        for (unsigned q = 0; q < 8u; ++q) { tt += sred[q]; mm += sred[8u + q]; }
        atomicAdd(stage + (size_t)b * 16u,        tt);
        atomicAdd(stage + (size_t)(8u + b) * 16u, mm);
    }
}

// ---------------------------------------------------------------------------
// Kernel 3: scale staged sums into d_out (overwrites poison).
__global__ void finalize_kernel(const float* __restrict__ stage,
                                float* __restrict__ out) {
    unsigned i = threadIdx.x;
    if (i < 16u) {
        float s = stage[i * 16u];
        float scale = (i < 8u) ? (1.0f / 2097152.0f)     // / 128^3
                               : (1.0f / 32512.0f);      // / (2*128^2 - 2*128)
        out[i] = s * scale;
    }
}

// ---------------------------------------------------------------------------
extern "C" void kernel_launch(void* const* d_in, const int* in_sizes, int n_in,
                              void* d_out, int out_size, void* d_ws, size_t ws_size,
                              hipStream_t stream) {
    const int*   idx  = (const int*)d_in[0];    // [8, 262144, 3] int32
    const float* vals = (const float*)d_in[1];  // [8, 262144] float32

    unsigned long long* rec2 = (unsigned long long*)d_ws;
    unsigned* gcur  = (unsigned*)(rec2 + REC2_U64);
    float*    stage = (float*)(gcur + NBKT);
    float*    out   = (float*)d_out;

    // Zero cursors (4 KiB) + stage (1 KiB).
    hipMemsetAsync(gcur, 0, NBKT * 4 + 256 * 4, stream);

    bin_kernel<<<NSEG, 256, 0, stream>>>(idx, vals, rec2, gcur);
    accum_kernel<<<2u * NBKT, 512, 0, stream>>>(rec2, gcur, stage);
    finalize_kernel<<<1, 64, 0, stream>>>(stage, out);
}